// Round 8
// baseline (31.558 us; speedup 1.0000x reference)
//
#include <hip/hip_runtime.h>
#include <hip/hip_bf16.h>
#include <math.h>

#define MF 32
#define EMB 78        // 2*32 + 2*(2^3-1)
#define NQ 12
#define NC 25
#define NSPAN 22
#define BLK 256
#define FSCALE 0.17677669529663688f   // 1/(sqrt(32)+1e-12)

typedef __attribute__((ext_vector_type(8))) short short8;
typedef __attribute__((ext_vector_type(4))) float f32x4;

// ws layout (dwords)
#define WS_A    0      // A fragments: 3 ktiles * 64 lanes * 4 dwords (bf16x2)
#define WS_SGSB 768    // (Sg,Sb) pairs, 16 q
#define WS_P    800    // poly table 16*22 float4 (byte 3200, 16B aligned)

__device__ __forceinline__ float fast_rcp(float x) { return __builtin_amdgcn_rcpf(x); }
__device__ __forceinline__ float satf(float x) { return fminf(fmaxf(x, 0.0f), 1.0f); }

// software RNE pack (setup / cold path)
__device__ __forceinline__ unsigned pack2(float a, float b) {
    __hip_bfloat16 ha = __float2bfloat16(a), hb = __float2bfloat16(b);
    unsigned short ua, ub;
    __builtin_memcpy(&ua, &ha, 2); __builtin_memcpy(&ub, &hb, 2);
    return (unsigned)ua | ((unsigned)ub << 16);
}

// manual RNE pack for finite non-NaN values — bit-identical to pack2, ~5 VALU ops
__device__ __forceinline__ unsigned bfpair(float a, float b) {
    unsigned ua = __builtin_bit_cast(unsigned, a);
    unsigned ub = __builtin_bit_cast(unsigned, b);
    ua += 0x7fffu + ((ua >> 16) & 1u);
    ub += 0x7fffu + ((ub >> 16) & 1u);
    return (ua >> 16) | (ub & 0xffff0000u);
}

// cubic B-spline basis N_{ii..ii+3} at s, span ii, open-uniform knots sat((idx-3)/22)
__device__ __forceinline__ float4 deboor4(float s, int ii) {
    const float c22 = 1.0f / 22.0f;
    float k_m2 = satf((float)(ii - 2) * c22);
    float k_m1 = satf((float)(ii - 1) * c22);
    float k_0  = satf((float)(ii)     * c22);
    float k_p1 = satf((float)(ii + 1) * c22);
    float k_p2 = satf((float)(ii + 2) * c22);
    float k_p3 = satf((float)(ii + 3) * c22);
    float l1 = s - k_0, l2 = s - k_m1, l3 = s - k_m2;
    float r1 = k_p1 - s, r2 = k_p2 - s, r3 = k_p3 - s;
    float t0 = fast_rcp(r1 + l1);
    float N0 = r1 * t0, N1 = l1 * t0;
    float ta = N0 * fast_rcp(r1 + l2);
    float tb = N1 * fast_rcp(r2 + l1);
    N0 = r1 * ta;
    N1 = fmaf(l2, ta, r2 * tb);
    float N2 = l1 * tb;
    float tc = N0 * fast_rcp(r1 + l3);
    float td = N1 * fast_rcp(r2 + l2);
    float te = N2 * fast_rcp(r3 + l1);
    N0 = r1 * tc;
    N1 = fmaf(l3, tc, r2 * td);
    N2 = fmaf(l2, td, r3 * te);
    float N3 = l1 * te;
    return make_float4(N0, N1, N2, N3);
}

__device__ __forceinline__ float wgf(const float* g, const float* W, int q, int k) {
    if (q >= NQ || k >= EMB) return 0.0f;
    float v = g[k] * W[q * EMB + k];
    return (k < 2 * MF) ? v * FSCALE : v;
}

__global__ __launch_bounds__(256) void pikan_setup(
    const float* __restrict__ g, const float* __restrict__ be,
    const float* __restrict__ W, const float* __restrict__ bi,
    const float* __restrict__ coeffs, const float* __restrict__ a,
    float* __restrict__ ws)
{
    const int tid = threadIdx.x;
    unsigned* wsu = (unsigned*)ws;

    // A fragments: lane l holds A[q=l&15][k = kt*32 + (l>>4)*8 + 2d .. +1]
    for (int i = tid; i < 768; i += 256) {
        int d = i & 3, l = (i >> 2) & 63, kt = i >> 8;
        int q = l & 15;
        int kb = kt * 32 + (l >> 4) * 8 + d * 2;
        wsu[WS_A + i] = pack2(wgf(g, W, q, kb), wgf(g, W, q, kb + 1));
    }
    // Sg/Sb (full f32 precision)
    if (tid < 16) {
        float sg = 0.f, sb = 0.f;
        if (tid < NQ) {
            for (int e = 0; e < EMB; ++e) {
                float w = W[tid * EMB + e];
                sg += g[e] * w;
                sb += be[e] * w;
            }
            sb += bi[tid];
        }
        ws[WS_SGSB + 2 * tid]     = sg;
        ws[WS_SGSB + 2 * tid + 1] = sb;
    }
    // per-(q,span) cubic poly of a_q*phi_q in local u = s*22 - span; q>=12 zeroed
    for (int i = tid; i < 16 * NSPAN; i += 256) {
        int q = i / NSPAN, ii = i - q * NSPAN;
        float4 o = make_float4(0.f, 0.f, 0.f, 0.f);
        if (q < NQ) {
            float f[4];
            #pragma unroll
            for (int j = 0; j < 4; ++j) {
                float u = (float)j / 3.0f;
                float s = ((float)ii + u) * (1.0f / 22.0f);
                float4 N = deboor4(s, ii);
                const float* cq = coeffs + q * NC + ii;
                f[j] = N.x * cq[0] + N.y * cq[1] + N.z * cq[2] + N.w * cq[3];
            }
            float c0 = f[0];
            float c1 = -5.5f * f[0] +  9.0f * f[1] -  4.5f * f[2] +  1.0f * f[3];
            float c2 =  9.0f * f[0] - 22.5f * f[1] + 18.0f * f[2] -  4.5f * f[3];
            float c3 = -4.5f * f[0] + 13.5f * f[1] - 13.5f * f[2] +  4.5f * f[3];
            float aq = a[q];
            o = make_float4(c0 * aq, c1 * aq, c2 * aq, c3 * aq);
        }
        reinterpret_cast<float4*>(ws + WS_P)[i] = o;
    }
}

__global__ __launch_bounds__(BLK, 4) void pikan_main(
    const float* __restrict__ xt, const float* __restrict__ Bf,
    const float* __restrict__ isc_p, const float* __restrict__ bout_p,
    const float* __restrict__ ws, float* __restrict__ out, int npts)
{
    __shared__ uint4  sEmb[4][256];              // per-wave 4KB staging
    __shared__ float4 sPoly[4][16 * NSPAN + 1];  // 4 lane-selected copies (+pad)

    const int tid = threadIdx.x;
    for (int i = tid; i < 16 * NSPAN; i += BLK) {
        float4 v = reinterpret_cast<const float4*>(ws + WS_P)[i];
        sPoly[0][i] = v; sPoly[1][i] = v; sPoly[2][i] = v; sPoly[3][i] = v;
    }
    __syncthreads();

    const int l = tid & 63, w = tid >> 6;
    const int g16 = l >> 4, c16 = l & 15;
    const int sw = (l >> 1) & 3;
    uint4* myEmb = sEmb[w];
    const float4* myPoly = sPoly[l & 3];

    // wave prologue: A fragments + LN-fold scalars to registers (coalesced)
    const uint4 af0 = reinterpret_cast<const uint4*>(ws)[0 * 64 + l];
    const uint4 af1 = reinterpret_cast<const uint4*>(ws)[1 * 64 + l];
    const uint4 af2 = reinterpret_cast<const uint4*>(ws)[2 * 64 + l];

    float sgq[4], sbq[4];
    #pragma unroll
    for (int r = 0; r < 4; ++r) {
        int q = g16 * 4 + r;
        sgq[r] = ws[WS_SGSB + 2 * q];
        sbq[r] = ws[WS_SGSB + 2 * q + 1];
    }

    const float kexp = -2.0f * isc_p[0] * 1.4426950408889634f;
    const float bout = bout_p[0];
    const int base = (blockIdx.x * 4 + w) * 128;

    const int pt0 = base + l, pt1 = base + 64 + l;
    float2 p0 = make_float2(0.f, 0.f), p1 = make_float2(0.f, 0.f);
    if (pt0 < npts) p0 = reinterpret_cast<const float2*>(xt)[pt0];
    if (pt1 < npts) p1 = reinterpret_cast<const float2*>(xt)[pt1];

    // ---- one pass: features -> stage -> 3 MFMA k-tiles; returns (mu, istd)
    auto do_pass = [&](float x, float t, f32x4 (&acc)[4]) -> float2 {
        #pragma unroll
        for (int n = 0; n < 4; ++n) acc[n] = (f32x4){0.f, 0.f, 0.f, 0.f};

        auto stage = [&](uint4 a0, uint4 a1, uint4 a2, uint4 a3) {
            myEmb[l * 4 + (0 ^ sw)] = a0;
            myEmb[l * 4 + (1 ^ sw)] = a1;
            myEmb[l * 4 + (2 ^ sw)] = a2;
            myEmb[l * 4 + (3 ^ sw)] = a3;
        };
        auto mfma_kt = [&](uint4 au) {
            short8 af = __builtin_bit_cast(short8, au);
            #pragma unroll
            for (int n = 0; n < 4; ++n) {
                int p = n * 16 + c16;
                uint4 bu = myEmb[p * 4 + (g16 ^ sw)];
                short8 bf = __builtin_bit_cast(short8, bu);
                acc[n] = __builtin_amdgcn_mfma_f32_16x16x32_bf16(af, bf, acc[n], 0, 0, 0);
            }
        };

        // Fourier (fscale folded into A); f32 sum exact; sumsq via sin^2+cos^2=1
        float sumf = 0.f;
        unsigned spk[16], cpk[16];
        #pragma unroll
        for (int mp = 0; mp < 16; ++mp) {
            float rev0 = fmaf(x, Bf[4 * mp + 0], t * Bf[4 * mp + 1]);
            float rev1 = fmaf(x, Bf[4 * mp + 2], t * Bf[4 * mp + 3]);
#if __has_builtin(__builtin_amdgcn_fractf)
            float f0 = __builtin_amdgcn_fractf(rev0);
            float f1 = __builtin_amdgcn_fractf(rev1);
#else
            float f0 = rev0 - floorf(rev0);
            float f1 = rev1 - floorf(rev1);
#endif
            float s0 = __builtin_amdgcn_sinf(f0), s1 = __builtin_amdgcn_sinf(f1);
            float c0 = __builtin_amdgcn_cosf(f0), c1 = __builtin_amdgcn_cosf(f1);
            sumf += (s0 + s1) + (c0 + c1);
            spk[mp] = bfpair(s0, s1);
            cpk[mp] = bfpair(c0, c1);
        }
        stage(make_uint4(spk[0], spk[1], spk[2],  spk[3]),
              make_uint4(spk[4], spk[5], spk[6],  spk[7]),
              make_uint4(spk[8], spk[9], spk[10], spk[11]),
              make_uint4(spk[12], spk[13], spk[14], spk[15]));
        mfma_kt(af0);
        stage(make_uint4(cpk[0], cpk[1], cpk[2],  cpk[3]),
              make_uint4(cpk[4], cpk[5], cpk[6],  cpk[7]),
              make_uint4(cpk[8], cpk[9], cpk[10], cpk[11]),
              make_uint4(cpk[12], cpk[13], cpk[14], cpk[15]));
        mfma_kt(af1);

        // Wavelets
        float w14[14];
        float sumw = 0.f, ssw = 0.f;
        {
            int o = 0;
            #pragma unroll
            for (int j = 0; j < 3; ++j) {
                const int nk = 1 << j;
                const float inv = (float)(2 * nk);
                #pragma unroll
                for (int k = 0; k < nk; ++k) {
                    float c = ((float)k + 0.5f) / (float)nk;
                    float v = (x - c) * inv, v2 = v * v;
                    float f = (1.0f - v2) * __expf(-0.5f * v2);
                    w14[o + k] = f; sumw += f; ssw = fmaf(f, f, ssw);
                }
                #pragma unroll
                for (int k = 0; k < nk; ++k) {
                    float c = ((float)k + 0.5f) / (float)nk;
                    float v = (t - c) * inv, v2 = v * v;
                    float f = (1.0f - v2) * __expf(-0.5f * v2);
                    w14[o + nk + k] = f; sumw += f; ssw = fmaf(f, f, ssw);
                }
                o += 2 * nk;
            }
        }
        stage(make_uint4(bfpair(w14[0], w14[1]), bfpair(w14[2], w14[3]),
                         bfpair(w14[4], w14[5]), bfpair(w14[6], w14[7])),
              make_uint4(bfpair(w14[8], w14[9]), bfpair(w14[10], w14[11]),
                         bfpair(w14[12], w14[13]), 0u),
              make_uint4(0u, 0u, 0u, 0u),
              make_uint4(0u, 0u, 0u, 0u));
        mfma_kt(af2);

        // LN scalars (exact f32; Fourier sumsq = FSCALE^2 * 32 by identity)
        const float sum = fmaf(FSCALE, sumf, sumw);
        const float ssq = fmaf(FSCALE * FSCALE, 32.0f, ssw);
        const float mu = sum * (1.0f / EMB);
        float var = fmaf(-mu, mu, ssq * (1.0f / EMB));
        var = fmaxf(var, 0.0f);
        const float istd = rsqrtf(var + 1e-5f);
        return make_float2(mu, istd);
    };

    f32x4 acc0[4], acc1[4];
    float2 st0 = do_pass(p0.x, p0.y, acc0);
    float2 st1 = do_pass(p1.x, p1.y, acc1);

    // broadcast LN scalars for all tiles of both passes
    float mun0[4], isn0[4], mun1[4], isn1[4];
    #pragma unroll
    for (int n = 0; n < 4; ++n) {
        mun0[n] = __shfl(st0.x, n * 16 + c16);
        isn0[n] = __shfl(st0.y, n * 16 + c16);
        mun1[n] = __shfl(st1.x, n * 16 + c16);
        isn1[n] = __shfl(st1.y, n * 16 + c16);
    }

    // ---- epilogue: 16 independent sigmoid+gather+poly chains per pass;
    // both passes written sequentially so the compiler interleaves 32 chains
    auto epi = [&](const f32x4 (&acc)[4], const float (&mun)[4],
                   const float (&isn)[4]) -> float {
        float yout = 0.f;
        #pragma unroll
        for (int n = 0; n < 4; ++n) {
            float yn = 0.f;
            #pragma unroll
            for (int r = 0; r < 4; ++r) {
                float uq = fmaf(isn[n], fmaf(-mun[n], sgq[r], acc[n][r]), sbq[r]);
                float e2 = __builtin_amdgcn_exp2f(kexp * uq);
                float s = fast_rcp(1.0f + e2);
                float v = s * 22.0f;
                int ii = (int)v; ii = ii > 21 ? 21 : ii;
                float uu = v - (float)ii;
                float4 cc = myPoly[(g16 * 4 + r) * NSPAN + ii];
                yn += fmaf(fmaf(fmaf(cc.w, uu, cc.z), uu, cc.y), uu, cc.x);
            }
            yn += __shfl_xor(yn, 16);
            yn += __shfl_xor(yn, 32);
            if (g16 == n) yout = yn;
        }
        return yout;
    };

    float y0 = epi(acc0, mun0, isn0);
    float y1 = epi(acc1, mun1, isn1);
    if (pt0 < npts) out[pt0] = y0 + bout;
    if (pt1 < npts) out[pt1] = y1 + bout;
}

extern "C" void kernel_launch(void* const* d_in, const int* in_sizes, int n_in,
                              void* d_out, int out_size, void* d_ws, size_t ws_size,
                              hipStream_t stream) {
    const float* xt          = (const float*)d_in[0];
    const float* Bf          = (const float*)d_in[1];
    const float* gamma       = (const float*)d_in[2];
    const float* beta        = (const float*)d_in[3];
    const float* W           = (const float*)d_in[4];
    const float* b_inner     = (const float*)d_in[5];
    const float* inner_scale = (const float*)d_in[6];
    const float* coeffs      = (const float*)d_in[7];
    const float* a           = (const float*)d_in[8];
    const float* b_out       = (const float*)d_in[9];
    float* out = (float*)d_out;
    float* ws  = (float*)d_ws;

    const int npts = in_sizes[0] / 2;
    pikan_setup<<<1, 256, 0, stream>>>(gamma, beta, W, b_inner, coeffs, a, ws);
    const int grid = (npts + 511) / 512;     // 512 points per block (2 per thread)
    pikan_main<<<grid, BLK, 0, stream>>>(xt, Bf, inner_scale, b_out, ws, out, npts);
}

// Round 9
// 31.374 us; speedup vs baseline: 1.0059x; 1.0059x over previous
//
#include <hip/hip_runtime.h>
#include <hip/hip_bf16.h>
#include <math.h>

#define MF 32
#define EMB 78        // 2*32 + 2*(2^3-1)
#define NQ 12
#define NC 25
#define NSPAN 22
#define BLK 256
#define FSCALE 0.17677669529663688f   // 1/(sqrt(32)+1e-12)

typedef __attribute__((ext_vector_type(8))) short short8;
typedef __attribute__((ext_vector_type(4))) float f32x4;

// ws layout (dwords)
#define WS_A    0      // A fragments: 3 ktiles * 64 lanes * 4 dwords (bf16x2)
#define WS_SGSB 768    // (Sg,Sb) pairs, 16 q
#define WS_P    800    // poly table 16*22 float4 (byte 3200, 16B aligned)

__device__ __forceinline__ float fast_rcp(float x) { return __builtin_amdgcn_rcpf(x); }
__device__ __forceinline__ float satf(float x) { return fminf(fmaxf(x, 0.0f), 1.0f); }

// software RNE pack (setup / cold path)
__device__ __forceinline__ unsigned pack2(float a, float b) {
    __hip_bfloat16 ha = __float2bfloat16(a), hb = __float2bfloat16(b);
    unsigned short ua, ub;
    __builtin_memcpy(&ua, &ha, 2); __builtin_memcpy(&ub, &hb, 2);
    return (unsigned)ua | ((unsigned)ub << 16);
}

// manual RNE pack for finite non-NaN values — bit-identical to pack2, ~5 VALU ops
__device__ __forceinline__ unsigned bfpair(float a, float b) {
    unsigned ua = __builtin_bit_cast(unsigned, a);
    unsigned ub = __builtin_bit_cast(unsigned, b);
    ua += 0x7fffu + ((ua >> 16) & 1u);
    ub += 0x7fffu + ((ub >> 16) & 1u);
    return (ua >> 16) | (ub & 0xffff0000u);
}

// cubic B-spline basis N_{ii..ii+3} at s, span ii, open-uniform knots sat((idx-3)/22)
__device__ __forceinline__ float4 deboor4(float s, int ii) {
    const float c22 = 1.0f / 22.0f;
    float k_m2 = satf((float)(ii - 2) * c22);
    float k_m1 = satf((float)(ii - 1) * c22);
    float k_0  = satf((float)(ii)     * c22);
    float k_p1 = satf((float)(ii + 1) * c22);
    float k_p2 = satf((float)(ii + 2) * c22);
    float k_p3 = satf((float)(ii + 3) * c22);
    float l1 = s - k_0, l2 = s - k_m1, l3 = s - k_m2;
    float r1 = k_p1 - s, r2 = k_p2 - s, r3 = k_p3 - s;
    float t0 = fast_rcp(r1 + l1);
    float N0 = r1 * t0, N1 = l1 * t0;
    float ta = N0 * fast_rcp(r1 + l2);
    float tb = N1 * fast_rcp(r2 + l1);
    N0 = r1 * ta;
    N1 = fmaf(l2, ta, r2 * tb);
    float N2 = l1 * tb;
    float tc = N0 * fast_rcp(r1 + l3);
    float td = N1 * fast_rcp(r2 + l2);
    float te = N2 * fast_rcp(r3 + l1);
    N0 = r1 * tc;
    N1 = fmaf(l3, tc, r2 * td);
    N2 = fmaf(l2, td, r3 * te);
    float N3 = l1 * te;
    return make_float4(N0, N1, N2, N3);
}

__device__ __forceinline__ float wgf(const float* g, const float* W, int q, int k) {
    if (q >= NQ || k >= EMB) return 0.0f;
    float v = g[k] * W[q * EMB + k];
    return (k < 2 * MF) ? v * FSCALE : v;
}

__global__ __launch_bounds__(256) void pikan_setup(
    const float* __restrict__ g, const float* __restrict__ be,
    const float* __restrict__ W, const float* __restrict__ bi,
    const float* __restrict__ coeffs, const float* __restrict__ a,
    float* __restrict__ ws)
{
    const int tid = threadIdx.x;
    unsigned* wsu = (unsigned*)ws;

    // A fragments: lane l holds A[q=l&15][k = kt*32 + (l>>4)*8 + 2d .. +1]
    for (int i = tid; i < 768; i += 256) {
        int d = i & 3, l = (i >> 2) & 63, kt = i >> 8;
        int q = l & 15;
        int kb = kt * 32 + (l >> 4) * 8 + d * 2;
        wsu[WS_A + i] = pack2(wgf(g, W, q, kb), wgf(g, W, q, kb + 1));
    }
    // Sg/Sb (full f32 precision)
    if (tid < 16) {
        float sg = 0.f, sb = 0.f;
        if (tid < NQ) {
            for (int e = 0; e < EMB; ++e) {
                float w = W[tid * EMB + e];
                sg += g[e] * w;
                sb += be[e] * w;
            }
            sb += bi[tid];
        }
        ws[WS_SGSB + 2 * tid]     = sg;
        ws[WS_SGSB + 2 * tid + 1] = sb;
    }
    // per-(q,span) cubic poly of a_q*phi_q in local u = s*22 - span; q>=12 zeroed
    for (int i = tid; i < 16 * NSPAN; i += 256) {
        int q = i / NSPAN, ii = i - q * NSPAN;
        float4 o = make_float4(0.f, 0.f, 0.f, 0.f);
        if (q < NQ) {
            float f[4];
            #pragma unroll
            for (int j = 0; j < 4; ++j) {
                float u = (float)j / 3.0f;
                float s = ((float)ii + u) * (1.0f / 22.0f);
                float4 N = deboor4(s, ii);
                const float* cq = coeffs + q * NC + ii;
                f[j] = N.x * cq[0] + N.y * cq[1] + N.z * cq[2] + N.w * cq[3];
            }
            float c0 = f[0];
            float c1 = -5.5f * f[0] +  9.0f * f[1] -  4.5f * f[2] +  1.0f * f[3];
            float c2 =  9.0f * f[0] - 22.5f * f[1] + 18.0f * f[2] -  4.5f * f[3];
            float c3 = -4.5f * f[0] + 13.5f * f[1] - 13.5f * f[2] +  4.5f * f[3];
            float aq = a[q];
            o = make_float4(c0 * aq, c1 * aq, c2 * aq, c3 * aq);
        }
        reinterpret_cast<float4*>(ws + WS_P)[i] = o;
    }
}

// waves_per_eu(4,4): pin the occupancy target to exactly 4 waves/EU so the
// register allocator budgets 128 VGPRs instead of clamping to 64 and spilling
// (round-8 counters: VGPR=64, 23 MB scratch writes). Residency is grid-limited
// to ~3.8 waves/SIMD anyway, so max=4 costs nothing.
__global__ __launch_bounds__(BLK) __attribute__((amdgpu_waves_per_eu(4, 4)))
void pikan_main(
    const float* __restrict__ xt, const float* __restrict__ Bf,
    const float* __restrict__ isc_p, const float* __restrict__ bout_p,
    const float* __restrict__ ws, float* __restrict__ out, int npts)
{
    __shared__ uint4  sEmb[4][256];              // per-wave 4KB staging
    __shared__ float4 sPoly[4][16 * NSPAN + 1];  // 4 lane-selected copies (+pad)

    const int tid = threadIdx.x;
    for (int i = tid; i < 16 * NSPAN; i += BLK) {
        float4 v = reinterpret_cast<const float4*>(ws + WS_P)[i];
        sPoly[0][i] = v; sPoly[1][i] = v; sPoly[2][i] = v; sPoly[3][i] = v;
    }
    __syncthreads();

    const int l = tid & 63, w = tid >> 6;
    const int g16 = l >> 4, c16 = l & 15;
    const int sw = (l >> 1) & 3;
    uint4* myEmb = sEmb[w];
    const float4* myPoly = sPoly[l & 3];

    // wave prologue: A fragments + LN-fold scalars to registers (coalesced)
    const uint4 af0 = reinterpret_cast<const uint4*>(ws)[0 * 64 + l];
    const uint4 af1 = reinterpret_cast<const uint4*>(ws)[1 * 64 + l];
    const uint4 af2 = reinterpret_cast<const uint4*>(ws)[2 * 64 + l];

    float sgq[4], sbq[4];
    #pragma unroll
    for (int r = 0; r < 4; ++r) {
        int q = g16 * 4 + r;
        sgq[r] = ws[WS_SGSB + 2 * q];
        sbq[r] = ws[WS_SGSB + 2 * q + 1];
    }

    const float kexp = -2.0f * isc_p[0] * 1.4426950408889634f;
    const float bout = bout_p[0];
    const int base = (blockIdx.x * 4 + w) * 128;

    const int pt0 = base + l, pt1 = base + 64 + l;
    float2 p0 = make_float2(0.f, 0.f), p1 = make_float2(0.f, 0.f);
    if (pt0 < npts) p0 = reinterpret_cast<const float2*>(xt)[pt0];
    if (pt1 < npts) p1 = reinterpret_cast<const float2*>(xt)[pt1];

    // ---- one pass: features -> stage -> 3 MFMA k-tiles; returns (mu, istd)
    auto do_pass = [&](float x, float t, f32x4 (&acc)[4]) -> float2 {
        #pragma unroll
        for (int n = 0; n < 4; ++n) acc[n] = (f32x4){0.f, 0.f, 0.f, 0.f};

        auto stage = [&](uint4 a0, uint4 a1, uint4 a2, uint4 a3) {
            myEmb[l * 4 + (0 ^ sw)] = a0;
            myEmb[l * 4 + (1 ^ sw)] = a1;
            myEmb[l * 4 + (2 ^ sw)] = a2;
            myEmb[l * 4 + (3 ^ sw)] = a3;
        };
        auto mfma_kt = [&](uint4 au) {
            short8 af = __builtin_bit_cast(short8, au);
            #pragma unroll
            for (int n = 0; n < 4; ++n) {
                int p = n * 16 + c16;
                uint4 bu = myEmb[p * 4 + (g16 ^ sw)];
                short8 bf = __builtin_bit_cast(short8, bu);
                acc[n] = __builtin_amdgcn_mfma_f32_16x16x32_bf16(af, bf, acc[n], 0, 0, 0);
            }
        };

        // Fourier (fscale folded into A); f32 sum exact; sumsq via sin^2+cos^2=1
        float sumf = 0.f;
        unsigned spk[16], cpk[16];
        #pragma unroll
        for (int mp = 0; mp < 16; ++mp) {
            float rev0 = fmaf(x, Bf[4 * mp + 0], t * Bf[4 * mp + 1]);
            float rev1 = fmaf(x, Bf[4 * mp + 2], t * Bf[4 * mp + 3]);
#if __has_builtin(__builtin_amdgcn_fractf)
            float f0 = __builtin_amdgcn_fractf(rev0);
            float f1 = __builtin_amdgcn_fractf(rev1);
#else
            float f0 = rev0 - floorf(rev0);
            float f1 = rev1 - floorf(rev1);
#endif
            float s0 = __builtin_amdgcn_sinf(f0), s1 = __builtin_amdgcn_sinf(f1);
            float c0 = __builtin_amdgcn_cosf(f0), c1 = __builtin_amdgcn_cosf(f1);
            sumf += (s0 + s1) + (c0 + c1);
            spk[mp] = bfpair(s0, s1);
            cpk[mp] = bfpair(c0, c1);
        }
        stage(make_uint4(spk[0], spk[1], spk[2],  spk[3]),
              make_uint4(spk[4], spk[5], spk[6],  spk[7]),
              make_uint4(spk[8], spk[9], spk[10], spk[11]),
              make_uint4(spk[12], spk[13], spk[14], spk[15]));
        mfma_kt(af0);
        stage(make_uint4(cpk[0], cpk[1], cpk[2],  cpk[3]),
              make_uint4(cpk[4], cpk[5], cpk[6],  cpk[7]),
              make_uint4(cpk[8], cpk[9], cpk[10], cpk[11]),
              make_uint4(cpk[12], cpk[13], cpk[14], cpk[15]));
        mfma_kt(af1);

        // Wavelets
        float w14[14];
        float sumw = 0.f, ssw = 0.f;
        {
            int o = 0;
            #pragma unroll
            for (int j = 0; j < 3; ++j) {
                const int nk = 1 << j;
                const float inv = (float)(2 * nk);
                #pragma unroll
                for (int k = 0; k < nk; ++k) {
                    float c = ((float)k + 0.5f) / (float)nk;
                    float v = (x - c) * inv, v2 = v * v;
                    float f = (1.0f - v2) * __expf(-0.5f * v2);
                    w14[o + k] = f; sumw += f; ssw = fmaf(f, f, ssw);
                }
                #pragma unroll
                for (int k = 0; k < nk; ++k) {
                    float c = ((float)k + 0.5f) / (float)nk;
                    float v = (t - c) * inv, v2 = v * v;
                    float f = (1.0f - v2) * __expf(-0.5f * v2);
                    w14[o + nk + k] = f; sumw += f; ssw = fmaf(f, f, ssw);
                }
                o += 2 * nk;
            }
        }
        stage(make_uint4(bfpair(w14[0], w14[1]), bfpair(w14[2], w14[3]),
                         bfpair(w14[4], w14[5]), bfpair(w14[6], w14[7])),
              make_uint4(bfpair(w14[8], w14[9]), bfpair(w14[10], w14[11]),
                         bfpair(w14[12], w14[13]), 0u),
              make_uint4(0u, 0u, 0u, 0u),
              make_uint4(0u, 0u, 0u, 0u));
        mfma_kt(af2);

        // LN scalars (exact f32; Fourier sumsq = FSCALE^2 * 32 by identity)
        const float sum = fmaf(FSCALE, sumf, sumw);
        const float ssq = fmaf(FSCALE * FSCALE, 32.0f, ssw);
        const float mu = sum * (1.0f / EMB);
        float var = fmaf(-mu, mu, ssq * (1.0f / EMB));
        var = fmaxf(var, 0.0f);
        const float istd = rsqrtf(var + 1e-5f);
        return make_float2(mu, istd);
    };

    f32x4 acc0[4], acc1[4];
    float2 st0 = do_pass(p0.x, p0.y, acc0);
    float2 st1 = do_pass(p1.x, p1.y, acc1);

    // broadcast LN scalars for all tiles of both passes
    float mun0[4], isn0[4], mun1[4], isn1[4];
    #pragma unroll
    for (int n = 0; n < 4; ++n) {
        mun0[n] = __shfl(st0.x, n * 16 + c16);
        isn0[n] = __shfl(st0.y, n * 16 + c16);
        mun1[n] = __shfl(st1.x, n * 16 + c16);
        isn1[n] = __shfl(st1.y, n * 16 + c16);
    }

    // ---- epilogue: 16 independent sigmoid+gather+poly chains per pass;
    // both passes written sequentially so the compiler interleaves 32 chains
    auto epi = [&](const f32x4 (&acc)[4], const float (&mun)[4],
                   const float (&isn)[4]) -> float {
        float yout = 0.f;
        #pragma unroll
        for (int n = 0; n < 4; ++n) {
            float yn = 0.f;
            #pragma unroll
            for (int r = 0; r < 4; ++r) {
                float uq = fmaf(isn[n], fmaf(-mun[n], sgq[r], acc[n][r]), sbq[r]);
                float e2 = __builtin_amdgcn_exp2f(kexp * uq);
                float s = fast_rcp(1.0f + e2);
                float v = s * 22.0f;
                int ii = (int)v; ii = ii > 21 ? 21 : ii;
                float uu = v - (float)ii;
                float4 cc = myPoly[(g16 * 4 + r) * NSPAN + ii];
                yn += fmaf(fmaf(fmaf(cc.w, uu, cc.z), uu, cc.y), uu, cc.x);
            }
            yn += __shfl_xor(yn, 16);
            yn += __shfl_xor(yn, 32);
            if (g16 == n) yout = yn;
        }
        return yout;
    };

    float y0 = epi(acc0, mun0, isn0);
    float y1 = epi(acc1, mun1, isn1);
    if (pt0 < npts) out[pt0] = y0 + bout;
    if (pt1 < npts) out[pt1] = y1 + bout;
}

extern "C" void kernel_launch(void* const* d_in, const int* in_sizes, int n_in,
                              void* d_out, int out_size, void* d_ws, size_t ws_size,
                              hipStream_t stream) {
    const float* xt          = (const float*)d_in[0];
    const float* Bf          = (const float*)d_in[1];
    const float* gamma       = (const float*)d_in[2];
    const float* beta        = (const float*)d_in[3];
    const float* W           = (const float*)d_in[4];
    const float* b_inner     = (const float*)d_in[5];
    const float* inner_scale = (const float*)d_in[6];
    const float* coeffs      = (const float*)d_in[7];
    const float* a           = (const float*)d_in[8];
    const float* b_out       = (const float*)d_in[9];
    float* out = (float*)d_out;
    float* ws  = (float*)d_ws;

    const int npts = in_sizes[0] / 2;
    pikan_setup<<<1, 256, 0, stream>>>(gamma, beta, W, b_inner, coeffs, a, ws);
    const int grid = (npts + 511) / 512;     // 512 points per block (2 per thread)
    pikan_main<<<grid, BLK, 0, stream>>>(xt, Bf, inner_scale, b_out, ws, out, npts);
}

// Round 10
// 27.641 us; speedup vs baseline: 1.1417x; 1.1351x over previous
//
#include <hip/hip_runtime.h>
#include <hip/hip_bf16.h>
#include <math.h>

#define MF 32
#define EMB 78        // 2*32 + 2*(2^3-1)
#define NQ 12
#define NC 25
#define NSPAN 22
#define BLK 256
#define FSCALE 0.17677669529663688f   // 1/(sqrt(32)+1e-12)

typedef __attribute__((ext_vector_type(8))) short short8;
typedef __attribute__((ext_vector_type(4))) float f32x4;

// ws layout (dwords)
#define WS_A    0      // A fragments: 3 ktiles * 64 lanes * 4 dwords (bf16x2)
#define WS_SGSB 768    // (Sg,Sb) pairs, 16 q
#define WS_P    800    // poly table 16*22 float4 (byte 3200, 16B aligned)

__device__ __forceinline__ float fast_rcp(float x) { return __builtin_amdgcn_rcpf(x); }
__device__ __forceinline__ float satf(float x) { return fminf(fmaxf(x, 0.0f), 1.0f); }

// software RNE pack (setup / cold path)
__device__ __forceinline__ unsigned pack2(float a, float b) {
    __hip_bfloat16 ha = __float2bfloat16(a), hb = __float2bfloat16(b);
    unsigned short ua, ub;
    __builtin_memcpy(&ua, &ha, 2); __builtin_memcpy(&ub, &hb, 2);
    return (unsigned)ua | ((unsigned)ub << 16);
}

// manual RNE pack for finite non-NaN values — bit-identical to pack2, ~5 VALU ops
// (verified passing with identical absmax in rounds 8-9)
__device__ __forceinline__ unsigned bfpair(float a, float b) {
    unsigned ua = __builtin_bit_cast(unsigned, a);
    unsigned ub = __builtin_bit_cast(unsigned, b);
    ua += 0x7fffu + ((ua >> 16) & 1u);
    ub += 0x7fffu + ((ub >> 16) & 1u);
    return (ua >> 16) | (ub & 0xffff0000u);
}

// cubic B-spline basis N_{ii..ii+3} at s, span ii, open-uniform knots sat((idx-3)/22)
__device__ __forceinline__ float4 deboor4(float s, int ii) {
    const float c22 = 1.0f / 22.0f;
    float k_m2 = satf((float)(ii - 2) * c22);
    float k_m1 = satf((float)(ii - 1) * c22);
    float k_0  = satf((float)(ii)     * c22);
    float k_p1 = satf((float)(ii + 1) * c22);
    float k_p2 = satf((float)(ii + 2) * c22);
    float k_p3 = satf((float)(ii + 3) * c22);
    float l1 = s - k_0, l2 = s - k_m1, l3 = s - k_m2;
    float r1 = k_p1 - s, r2 = k_p2 - s, r3 = k_p3 - s;
    float t0 = fast_rcp(r1 + l1);
    float N0 = r1 * t0, N1 = l1 * t0;
    float ta = N0 * fast_rcp(r1 + l2);
    float tb = N1 * fast_rcp(r2 + l1);
    N0 = r1 * ta;
    N1 = fmaf(l2, ta, r2 * tb);
    float N2 = l1 * tb;
    float tc = N0 * fast_rcp(r1 + l3);
    float td = N1 * fast_rcp(r2 + l2);
    float te = N2 * fast_rcp(r3 + l1);
    N0 = r1 * tc;
    N1 = fmaf(l3, tc, r2 * td);
    N2 = fmaf(l2, td, r3 * te);
    float N3 = l1 * te;
    return make_float4(N0, N1, N2, N3);
}

__device__ __forceinline__ float wgf(const float* g, const float* W, int q, int k) {
    if (q >= NQ || k >= EMB) return 0.0f;
    float v = g[k] * W[q * EMB + k];
    return (k < 2 * MF) ? v * FSCALE : v;
}

__global__ __launch_bounds__(256) void pikan_setup(
    const float* __restrict__ g, const float* __restrict__ be,
    const float* __restrict__ W, const float* __restrict__ bi,
    const float* __restrict__ coeffs, const float* __restrict__ a,
    float* __restrict__ ws)
{
    const int tid = threadIdx.x;
    unsigned* wsu = (unsigned*)ws;

    // A fragments: lane l holds A[q=l&15][k = kt*32 + (l>>4)*8 + 2d .. +1]
    for (int i = tid; i < 768; i += 256) {
        int d = i & 3, l = (i >> 2) & 63, kt = i >> 8;
        int q = l & 15;
        int kb = kt * 32 + (l >> 4) * 8 + d * 2;
        wsu[WS_A + i] = pack2(wgf(g, W, q, kb), wgf(g, W, q, kb + 1));
    }
    // Sg/Sb (full f32 precision)
    if (tid < 16) {
        float sg = 0.f, sb = 0.f;
        if (tid < NQ) {
            for (int e = 0; e < EMB; ++e) {
                float w = W[tid * EMB + e];
                sg += g[e] * w;
                sb += be[e] * w;
            }
            sb += bi[tid];
        }
        ws[WS_SGSB + 2 * tid]     = sg;
        ws[WS_SGSB + 2 * tid + 1] = sb;
    }
    // per-(q,span) cubic poly of a_q*phi_q in local u = s*22 - span; q>=12 zeroed
    for (int i = tid; i < 16 * NSPAN; i += 256) {
        int q = i / NSPAN, ii = i - q * NSPAN;
        float4 o = make_float4(0.f, 0.f, 0.f, 0.f);
        if (q < NQ) {
            float f[4];
            #pragma unroll
            for (int j = 0; j < 4; ++j) {
                float u = (float)j / 3.0f;
                float s = ((float)ii + u) * (1.0f / 22.0f);
                float4 N = deboor4(s, ii);
                const float* cq = coeffs + q * NC + ii;
                f[j] = N.x * cq[0] + N.y * cq[1] + N.z * cq[2] + N.w * cq[3];
            }
            float c0 = f[0];
            float c1 = -5.5f * f[0] +  9.0f * f[1] -  4.5f * f[2] +  1.0f * f[3];
            float c2 =  9.0f * f[0] - 22.5f * f[1] + 18.0f * f[2] -  4.5f * f[3];
            float c3 = -4.5f * f[0] + 13.5f * f[1] - 13.5f * f[2] +  4.5f * f[3];
            float aq = a[q];
            o = make_float4(c0 * aq, c1 * aq, c2 * aq, c3 * aq);
        }
        reinterpret_cast<float4*>(ws + WS_P)[i] = o;
    }
}

// waves_per_eu(4,4): force the allocator to the 128-VGPR tier. Round-8 counters
// proved the default heuristic clamps to VGPR=64 (8-wave tier) and spills
// ~23 MB to scratch; the grid only sustains ~3.8 waves/SIMD, so the 4-wave
// tier loses zero residency.
__global__ __launch_bounds__(BLK) __attribute__((amdgpu_waves_per_eu(4, 4)))
void pikan_main(
    const float* __restrict__ xt, const float* __restrict__ Bf,
    const float* __restrict__ isc_p, const float* __restrict__ bout_p,
    const float* __restrict__ ws, float* __restrict__ out, int npts)
{
    __shared__ uint4  sEmb[4][256];          // per-wave 4KB staging
    __shared__ float4 sPoly[16 * NSPAN];     // poly table (single copy, as round 3)

    const int tid = threadIdx.x;
    for (int i = tid; i < 16 * NSPAN; i += BLK)
        sPoly[i] = reinterpret_cast<const float4*>(ws + WS_P)[i];
    __syncthreads();

    const int l = tid & 63, w = tid >> 6;
    const int g16 = l >> 4, c16 = l & 15;
    const int sw = (l >> 1) & 3;
    uint4* myEmb = sEmb[w];

    float sgq[4], sbq[4];
    #pragma unroll
    for (int r = 0; r < 4; ++r) {
        int q = g16 * 4 + r;
        sgq[r] = ws[WS_SGSB + 2 * q];
        sbq[r] = ws[WS_SGSB + 2 * q + 1];
    }
    const float kexp = -2.0f * isc_p[0] * 1.4426950408889634f;
    const float bout = bout_p[0];
    const int base = (blockIdx.x * 4 + w) * 128;

    #pragma unroll 1
    for (int pass = 0; pass < 2; ++pass) {
        const int pbase = base + pass * 64;
        const int pt = pbase + l;
        const bool valid = pt < npts;
        float x = 0.f, t = 0.f;
        if (valid) { float2 p = reinterpret_cast<const float2*>(xt)[pt]; x = p.x; t = p.y; }

        f32x4 acc[4];
        #pragma unroll
        for (int n = 0; n < 4; ++n) acc[n] = (f32x4){0.f, 0.f, 0.f, 0.f};

        auto stage = [&](uint4 a0, uint4 a1, uint4 a2, uint4 a3) {
            myEmb[l * 4 + (0 ^ sw)] = a0;
            myEmb[l * 4 + (1 ^ sw)] = a1;
            myEmb[l * 4 + (2 ^ sw)] = a2;
            myEmb[l * 4 + (3 ^ sw)] = a3;
        };
        auto mfma_kt = [&](int kt) {
            uint4 au = reinterpret_cast<const uint4*>(ws)[kt * 64 + l];
            short8 af = __builtin_bit_cast(short8, au);
            #pragma unroll
            for (int n = 0; n < 4; ++n) {
                int p = n * 16 + c16;
                uint4 bu = myEmb[p * 4 + (g16 ^ sw)];
                short8 bf = __builtin_bit_cast(short8, bu);
                acc[n] = __builtin_amdgcn_mfma_f32_16x16x32_bf16(af, bf, acc[n], 0, 0, 0);
            }
        };

        // ---- Fourier (fscale folded into A); f32 stats exact
        float sumf = 0.f, ssf = 0.f;
        unsigned spk[16], cpk[16];
        #pragma unroll
        for (int mp = 0; mp < 16; ++mp) {
            float rev0 = fmaf(x, Bf[4 * mp + 0], t * Bf[4 * mp + 1]);
            float rev1 = fmaf(x, Bf[4 * mp + 2], t * Bf[4 * mp + 3]);
#if __has_builtin(__builtin_amdgcn_fractf)
            float f0 = __builtin_amdgcn_fractf(rev0);
            float f1 = __builtin_amdgcn_fractf(rev1);
#else
            float f0 = rev0 - floorf(rev0);
            float f1 = rev1 - floorf(rev1);
#endif
            float s0 = __builtin_amdgcn_sinf(f0), s1 = __builtin_amdgcn_sinf(f1);
            float c0 = __builtin_amdgcn_cosf(f0), c1 = __builtin_amdgcn_cosf(f1);
            sumf += (s0 + s1) + (c0 + c1);
            ssf = fmaf(s0, s0, fmaf(s1, s1, fmaf(c0, c0, fmaf(c1, c1, ssf))));
            spk[mp] = bfpair(s0, s1);
            cpk[mp] = bfpair(c0, c1);
        }
        stage(make_uint4(spk[0], spk[1], spk[2],  spk[3]),
              make_uint4(spk[4], spk[5], spk[6],  spk[7]),
              make_uint4(spk[8], spk[9], spk[10], spk[11]),
              make_uint4(spk[12], spk[13], spk[14], spk[15]));
        mfma_kt(0);
        stage(make_uint4(cpk[0], cpk[1], cpk[2],  cpk[3]),
              make_uint4(cpk[4], cpk[5], cpk[6],  cpk[7]),
              make_uint4(cpk[8], cpk[9], cpk[10], cpk[11]),
              make_uint4(cpk[12], cpk[13], cpk[14], cpk[15]));
        mfma_kt(1);

        // ---- Wavelets
        float w14[14];
        float sumw = 0.f, ssw = 0.f;
        {
            int o = 0;
            #pragma unroll
            for (int j = 0; j < 3; ++j) {
                const int nk = 1 << j;
                const float inv = (float)(2 * nk);
                #pragma unroll
                for (int k = 0; k < nk; ++k) {
                    float c = ((float)k + 0.5f) / (float)nk;
                    float v = (x - c) * inv, v2 = v * v;
                    float f = (1.0f - v2) * __expf(-0.5f * v2);
                    w14[o + k] = f; sumw += f; ssw = fmaf(f, f, ssw);
                }
                #pragma unroll
                for (int k = 0; k < nk; ++k) {
                    float c = ((float)k + 0.5f) / (float)nk;
                    float v = (t - c) * inv, v2 = v * v;
                    float f = (1.0f - v2) * __expf(-0.5f * v2);
                    w14[o + nk + k] = f; sumw += f; ssw = fmaf(f, f, ssw);
                }
                o += 2 * nk;
            }
        }
        stage(make_uint4(bfpair(w14[0], w14[1]), bfpair(w14[2], w14[3]),
                         bfpair(w14[4], w14[5]), bfpair(w14[6], w14[7])),
              make_uint4(bfpair(w14[8], w14[9]), bfpair(w14[10], w14[11]),
                         bfpair(w14[12], w14[13]), 0u),
              make_uint4(0u, 0u, 0u, 0u),
              make_uint4(0u, 0u, 0u, 0u));
        mfma_kt(2);

        // ---- LN scalars (exact f32 path)
        const float sum = fmaf(FSCALE, sumf, sumw);
        const float ssq = fmaf(FSCALE * FSCALE, ssf, ssw);
        const float mu = sum * (1.0f / EMB);
        float var = fmaf(-mu, mu, ssq * (1.0f / EMB));
        var = fmaxf(var, 0.0f);
        const float istd = rsqrtf(var + 1e-5f);

        // ---- epilogue: sigmoid + spline poly per (q,point); reduce q across lanes
        float yout = 0.f;
        #pragma unroll
        for (int n = 0; n < 4; ++n) {
            float mun  = __shfl(mu,   n * 16 + c16);
            float istn = __shfl(istd, n * 16 + c16);
            float yn = 0.f;
            #pragma unroll
            for (int r = 0; r < 4; ++r) {
                float uq = fmaf(istn, fmaf(-mun, sgq[r], acc[n][r]), sbq[r]);
                float e2 = __builtin_amdgcn_exp2f(kexp * uq);
                float s = fast_rcp(1.0f + e2);
                float v = s * 22.0f;
                int ii = (int)v; ii = ii > 21 ? 21 : ii;
                float uu = v - (float)ii;
                float4 cc = sPoly[(g16 * 4 + r) * NSPAN + ii];
                yn += fmaf(fmaf(fmaf(cc.w, uu, cc.z), uu, cc.y), uu, cc.x);
            }
            yn += __shfl_xor(yn, 16);
            yn += __shfl_xor(yn, 32);
            if (g16 == n) yout = yn;
        }
        if (valid) out[pt] = yout + bout;
    }
}

extern "C" void kernel_launch(void* const* d_in, const int* in_sizes, int n_in,
                              void* d_out, int out_size, void* d_ws, size_t ws_size,
                              hipStream_t stream) {
    const float* xt          = (const float*)d_in[0];
    const float* Bf          = (const float*)d_in[1];
    const float* gamma       = (const float*)d_in[2];
    const float* beta        = (const float*)d_in[3];
    const float* W           = (const float*)d_in[4];
    const float* b_inner     = (const float*)d_in[5];
    const float* inner_scale = (const float*)d_in[6];
    const float* coeffs      = (const float*)d_in[7];
    const float* a           = (const float*)d_in[8];
    const float* b_out       = (const float*)d_in[9];
    float* out = (float*)d_out;
    float* ws  = (float*)d_ws;

    const int npts = in_sizes[0] / 2;
    pikan_setup<<<1, 256, 0, stream>>>(gamma, beta, W, b_inner, coeffs, a, ws);
    const int grid = (npts + 511) / 512;     // 512 points per block (2 per thread)
    pikan_main<<<grid, BLK, 0, stream>>>(xt, Bf, inner_scale, b_out, ws, out, npts);
}

// Round 11
// 26.092 us; speedup vs baseline: 1.2095x; 1.0593x over previous
//
#include <hip/hip_runtime.h>
#include <hip/hip_bf16.h>
#include <math.h>

#define MF 32
#define EMB 78        // 2*32 + 2*(2^3-1)
#define NQ 12
#define NC 25
#define NSPAN 22
#define BLK 512
#define NWAVE 8
#define FSCALE 0.17677669529663688f   // 1/(sqrt(32)+1e-12)

typedef __attribute__((ext_vector_type(8))) short short8;
typedef __attribute__((ext_vector_type(4))) float f32x4;

// ws layout (dwords)
#define WS_A    0      // A fragments: 3 ktiles * 64 lanes * 4 dwords (bf16x2)
#define WS_SGSB 768    // (Sg,Sb) pairs, 16 q
#define WS_P    800    // poly table 16*22 float4 (byte 3200, 16B aligned)

__device__ __forceinline__ float fast_rcp(float x) { return __builtin_amdgcn_rcpf(x); }
__device__ __forceinline__ float satf(float x) { return fminf(fmaxf(x, 0.0f), 1.0f); }

// software RNE pack (setup / cold path)
__device__ __forceinline__ unsigned pack2(float a, float b) {
    __hip_bfloat16 ha = __float2bfloat16(a), hb = __float2bfloat16(b);
    unsigned short ua, ub;
    __builtin_memcpy(&ua, &ha, 2); __builtin_memcpy(&ub, &hb, 2);
    return (unsigned)ua | ((unsigned)ub << 16);
}

// manual RNE pack, bit-identical to pack2 for finite non-NaN (verified R8-R10)
__device__ __forceinline__ unsigned bfpair(float a, float b) {
    unsigned ua = __builtin_bit_cast(unsigned, a);
    unsigned ub = __builtin_bit_cast(unsigned, b);
    ua += 0x7fffu + ((ua >> 16) & 1u);
    ub += 0x7fffu + ((ub >> 16) & 1u);
    return (ua >> 16) | (ub & 0xffff0000u);
}

// cubic B-spline basis N_{ii..ii+3} at s, span ii, open-uniform knots sat((idx-3)/22)
__device__ __forceinline__ float4 deboor4(float s, int ii) {
    const float c22 = 1.0f / 22.0f;
    float k_m2 = satf((float)(ii - 2) * c22);
    float k_m1 = satf((float)(ii - 1) * c22);
    float k_0  = satf((float)(ii)     * c22);
    float k_p1 = satf((float)(ii + 1) * c22);
    float k_p2 = satf((float)(ii + 2) * c22);
    float k_p3 = satf((float)(ii + 3) * c22);
    float l1 = s - k_0, l2 = s - k_m1, l3 = s - k_m2;
    float r1 = k_p1 - s, r2 = k_p2 - s, r3 = k_p3 - s;
    float t0 = fast_rcp(r1 + l1);
    float N0 = r1 * t0, N1 = l1 * t0;
    float ta = N0 * fast_rcp(r1 + l2);
    float tb = N1 * fast_rcp(r2 + l1);
    N0 = r1 * ta;
    N1 = fmaf(l2, ta, r2 * tb);
    float N2 = l1 * tb;
    float tc = N0 * fast_rcp(r1 + l3);
    float td = N1 * fast_rcp(r2 + l2);
    float te = N2 * fast_rcp(r3 + l1);
    N0 = r1 * tc;
    N1 = fmaf(l3, tc, r2 * td);
    N2 = fmaf(l2, td, r3 * te);
    float N3 = l1 * te;
    return make_float4(N0, N1, N2, N3);
}

// feature index for (ktile, kk within tile): kt 0/1 interleave (sin_m, cos_m)
__device__ __forceinline__ int kmap(int kt, int kk) {
    if (kt < 2) {
        int m = kt * 16 + (kk >> 1);
        return (kk & 1) ? (MF + m) : m;
    }
    return 64 + kk;   // wavelets (>=EMB handled by wgf -> 0)
}

__device__ __forceinline__ float wgf(const float* g, const float* W, int q, int k) {
    if (q >= NQ || k >= EMB) return 0.0f;
    float v = g[k] * W[q * EMB + k];
    return (k < 2 * MF) ? v * FSCALE : v;
}

__global__ __launch_bounds__(256) void pikan_setup(
    const float* __restrict__ g, const float* __restrict__ be,
    const float* __restrict__ W, const float* __restrict__ bi,
    const float* __restrict__ coeffs, const float* __restrict__ a,
    float* __restrict__ ws)
{
    const int tid = threadIdx.x;
    unsigned* wsu = (unsigned*)ws;

    // A fragments, k reordered per kmap: lane l holds q=l&15, kk = (l>>4)*8 + 2d..+1
    for (int i = tid; i < 768; i += 256) {
        int d = i & 3, l = (i >> 2) & 63, kt = i >> 8;
        int q = l & 15;
        int kk = (l >> 4) * 8 + d * 2;
        wsu[WS_A + i] = pack2(wgf(g, W, q, kmap(kt, kk)),
                              wgf(g, W, q, kmap(kt, kk + 1)));
    }
    // Sg/Sb (full f32 precision; order-independent sums)
    if (tid < 16) {
        float sg = 0.f, sb = 0.f;
        if (tid < NQ) {
            for (int e = 0; e < EMB; ++e) {
                float w = W[tid * EMB + e];
                sg += g[e] * w;
                sb += be[e] * w;
            }
            sb += bi[tid];
        }
        ws[WS_SGSB + 2 * tid]     = sg;
        ws[WS_SGSB + 2 * tid + 1] = sb;
    }
    // per-(q,span) cubic poly of a_q*phi_q in local u = s*22 - span; q>=12 zeroed
    for (int i = tid; i < 16 * NSPAN; i += 256) {
        int q = i / NSPAN, ii = i - q * NSPAN;
        float4 o = make_float4(0.f, 0.f, 0.f, 0.f);
        if (q < NQ) {
            float f[4];
            #pragma unroll
            for (int j = 0; j < 4; ++j) {
                float u = (float)j / 3.0f;
                float s = ((float)ii + u) * (1.0f / 22.0f);
                float4 N = deboor4(s, ii);
                const float* cq = coeffs + q * NC + ii;
                f[j] = N.x * cq[0] + N.y * cq[1] + N.z * cq[2] + N.w * cq[3];
            }
            float c0 = f[0];
            float c1 = -5.5f * f[0] +  9.0f * f[1] -  4.5f * f[2] +  1.0f * f[3];
            float c2 =  9.0f * f[0] - 22.5f * f[1] + 18.0f * f[2] -  4.5f * f[3];
            float c3 = -4.5f * f[0] + 13.5f * f[1] - 13.5f * f[2] +  4.5f * f[3];
            float aq = a[q];
            o = make_float4(c0 * aq, c1 * aq, c2 * aq, c3 * aq);
        }
        reinterpret_cast<float4*>(ws + WS_P)[i] = o;
    }
}

// 1 point/thread, 8 waves/block. launch_bounds(512,8): 8 waves/EU -> VGPR<=64.
// The interleaved (sin,cos) k-order lets each uint4 go to LDS as computed, so
// live state genuinely fits 64 regs (no round-8-style spill).
__global__ __launch_bounds__(BLK, 8) void pikan_main(
    const float* __restrict__ xt, const float* __restrict__ Bf,
    const float* __restrict__ isc_p, const float* __restrict__ bout_p,
    const float* __restrict__ ws, float* __restrict__ out, int npts)
{
    __shared__ uint4  sEmb[NWAVE][256];      // per-wave 4KB staging (32KB)
    __shared__ float4 sPoly[16 * NSPAN];     // 5.5KB poly table

    const int tid = threadIdx.x;
    for (int i = tid; i < 16 * NSPAN; i += BLK)
        sPoly[i] = reinterpret_cast<const float4*>(ws + WS_P)[i];
    __syncthreads();

    const int l = tid & 63, w = tid >> 6;
    const int g16 = l >> 4, c16 = l & 15;
    const int sw = (l >> 1) & 3;
    uint4* myEmb = sEmb[w];

    const int pt = blockIdx.x * BLK + tid;
    const bool valid = pt < npts;
    float x = 0.f, t = 0.f;
    if (valid) { float2 p = reinterpret_cast<const float2*>(xt)[pt]; x = p.x; t = p.y; }

    f32x4 acc[4];
    #pragma unroll
    for (int n = 0; n < 4; ++n) acc[n] = (f32x4){0.f, 0.f, 0.f, 0.f};

    auto stW = [&](int d, uint4 v) { myEmb[l * 4 + (d ^ sw)] = v; };
    auto mfma_kt = [&](int kt) {
        uint4 au = reinterpret_cast<const uint4*>(ws)[kt * 64 + l];
        short8 af = __builtin_bit_cast(short8, au);
        #pragma unroll
        for (int n = 0; n < 4; ++n) {
            int p = n * 16 + c16;
            uint4 bu = myEmb[p * 4 + (g16 ^ sw)];
            short8 bf = __builtin_bit_cast(short8, bu);
            acc[n] = __builtin_amdgcn_mfma_f32_16x16x32_bf16(af, bf, acc[n], 0, 0, 0);
        }
    };

    // ---- Fourier, k-tiles 0/1: dword = (sin_m, cos_m); stage each uint4 as built
    float sumf = 0.f;
    #pragma unroll
    for (int kt = 0; kt < 2; ++kt) {
        #pragma unroll
        for (int d = 0; d < 4; ++d) {
            unsigned dw[4];
            #pragma unroll
            for (int j = 0; j < 4; ++j) {
                int m = kt * 16 + d * 4 + j;
                float rev = fmaf(x, Bf[2 * m], t * Bf[2 * m + 1]);
#if __has_builtin(__builtin_amdgcn_fractf)
                float fr = __builtin_amdgcn_fractf(rev);
#else
                float fr = rev - floorf(rev);
#endif
                float s0 = __builtin_amdgcn_sinf(fr);
                float c0 = __builtin_amdgcn_cosf(fr);
                sumf += s0 + c0;
                dw[j] = bfpair(s0, c0);
            }
            stW(d, make_uint4(dw[0], dw[1], dw[2], dw[3]));
        }
        mfma_kt(kt);
    }

    // ---- Wavelets (k-tile 2), feature order preserved
    float w14[14];
    float sumw = 0.f, ssw = 0.f;
    {
        int o = 0;
        #pragma unroll
        for (int j = 0; j < 3; ++j) {
            const int nk = 1 << j;
            const float inv = (float)(2 * nk);
            #pragma unroll
            for (int k = 0; k < nk; ++k) {
                float c = ((float)k + 0.5f) / (float)nk;
                float v = (x - c) * inv, v2 = v * v;
                float f = (1.0f - v2) * __expf(-0.5f * v2);
                w14[o + k] = f; sumw += f; ssw = fmaf(f, f, ssw);
            }
            #pragma unroll
            for (int k = 0; k < nk; ++k) {
                float c = ((float)k + 0.5f) / (float)nk;
                float v = (t - c) * inv, v2 = v * v;
                float f = (1.0f - v2) * __expf(-0.5f * v2);
                w14[o + nk + k] = f; sumw += f; ssw = fmaf(f, f, ssw);
            }
            o += 2 * nk;
        }
    }
    stW(0, make_uint4(bfpair(w14[0], w14[1]), bfpair(w14[2], w14[3]),
                      bfpair(w14[4], w14[5]), bfpair(w14[6], w14[7])));
    stW(1, make_uint4(bfpair(w14[8], w14[9]), bfpair(w14[10], w14[11]),
                      bfpair(w14[12], w14[13]), 0u));
    stW(2, make_uint4(0u, 0u, 0u, 0u));
    stW(3, make_uint4(0u, 0u, 0u, 0u));
    mfma_kt(2);

    // ---- LN scalars (exact f32; Fourier sumsq = FSCALE^2*32 by sin^2+cos^2=1)
    const float sum = fmaf(FSCALE, sumf, sumw);
    const float ssq = fmaf(FSCALE * FSCALE, 32.0f, ssw);
    const float mu = sum * (1.0f / EMB);
    float var = fmaf(-mu, mu, ssq * (1.0f / EMB));
    var = fmaxf(var, 0.0f);
    const float istd = rsqrtf(var + 1e-5f);

    // ---- epilogue
    float sgq[4], sbq[4];
    #pragma unroll
    for (int r = 0; r < 4; ++r) {
        int q = g16 * 4 + r;
        sgq[r] = ws[WS_SGSB + 2 * q];
        sbq[r] = ws[WS_SGSB + 2 * q + 1];
    }
    const float kexp = -2.0f * isc_p[0] * 1.4426950408889634f;
    const float bout = bout_p[0];

    float yout = 0.f;
    #pragma unroll
    for (int n = 0; n < 4; ++n) {
        float mun  = __shfl(mu,   n * 16 + c16);
        float istn = __shfl(istd, n * 16 + c16);
        float yn = 0.f;
        #pragma unroll
        for (int r = 0; r < 4; ++r) {
            float uq = fmaf(istn, fmaf(-mun, sgq[r], acc[n][r]), sbq[r]);
            float e2 = __builtin_amdgcn_exp2f(kexp * uq);
            float s = fast_rcp(1.0f + e2);
            float v = s * 22.0f;
            int ii = (int)v; ii = ii > 21 ? 21 : ii;
            float uu = v - (float)ii;
            float4 cc = sPoly[(g16 * 4 + r) * NSPAN + ii];
            yn += fmaf(fmaf(fmaf(cc.w, uu, cc.z), uu, cc.y), uu, cc.x);
        }
        yn += __shfl_xor(yn, 16);
        yn += __shfl_xor(yn, 32);
        if (g16 == n) yout = yn;
    }
    if (valid) out[pt] = yout + bout;
}

extern "C" void kernel_launch(void* const* d_in, const int* in_sizes, int n_in,
                              void* d_out, int out_size, void* d_ws, size_t ws_size,
                              hipStream_t stream) {
    const float* xt          = (const float*)d_in[0];
    const float* Bf          = (const float*)d_in[1];
    const float* gamma       = (const float*)d_in[2];
    const float* beta        = (const float*)d_in[3];
    const float* W           = (const float*)d_in[4];
    const float* b_inner     = (const float*)d_in[5];
    const float* inner_scale = (const float*)d_in[6];
    const float* coeffs      = (const float*)d_in[7];
    const float* a           = (const float*)d_in[8];
    const float* b_out       = (const float*)d_in[9];
    float* out = (float*)d_out;
    float* ws  = (float*)d_ws;

    const int npts = in_sizes[0] / 2;
    pikan_setup<<<1, 256, 0, stream>>>(gamma, beta, W, b_inner, coeffs, a, ws);
    const int grid = (npts + BLK - 1) / BLK;   // 1 point per thread
    pikan_main<<<grid, BLK, 0, stream>>>(xt, Bf, inner_scale, b_out, ws, out, npts);
}